// Round 17
// baseline (268.095 us; speedup 1.0000x reference)
//
#include <hip/hip_runtime.h>
#include <hip/hip_bf16.h>

typedef short short8 __attribute__((ext_vector_type(8)));
typedef float f32x4 __attribute__((ext_vector_type(4)));

#define S_   64
#define NL_  5000
#define PD_  1024
#define LD_  768
#define DIM_ 512
#define OD_  512

#define BK     32          // panel/pack granularity (unchanged layouts)
#define NWIN4  4           // main-loop windows, 128-wide K each
#define KSTEPS 16          // DIM_/BK
#define NT_M   79          // ceil(5000/64) n-tiles
#define HL_RT  157         // ceil(5000/32) row-tiles for hl

__device__ __forceinline__ ushort f2bf(float f) {
    union { float f; unsigned u; } v; v.f = f;
    unsigned r = v.u + 0x7fffu + ((v.u >> 16) & 1u);   // RNE
    return (ushort)(r >> 16);
}
__device__ __forceinline__ float bf2f(ushort h) {
    union { unsigned u; float f; } v; v.u = ((unsigned)h) << 16;
    return v.f;
}
// XOR swizzle for 64B-stride row tiles (rows 0..255): conflict-free for the
// pack write (4 lanes/row x 4 kslots) and 16-row x 4-kslot fragment read
// (0 conflicts r6..r16). swz(row+16,k)=swz(row,k)+1024; +128 rows = +8192.
__device__ __forceinline__ int swz(int row, int kslot) {
    return (row * 64 + kslot * 16) ^ (((row >> 1) & 7) << 4);
}

// ---- coalesced small GEMM: C[s][o0..o0+7] = A[64][K] @ W[.][K]^T (+bias) ---
__device__ __forceinline__ void proj8(
    float* Af /* [64][258] */, const float* __restrict__ A, int lda, int K,
    const float* __restrict__ W, int ldw, const float* __restrict__ bias,
    float* __restrict__ C, int o0, int t) {
    const int s = t & 63, og = t >> 6;
    const int oA = o0 + og * 2, oB = oA + 1;
    float acc0 = 0.f, acc1 = 0.f;
    for (int ck = 0; ck < K; ck += 256) {
        __syncthreads();
#pragma unroll
        for (int it = 0; it < 16; it++) {
            int r = it * 4 + (t >> 6);
            float4 v = *(const float4*)(A + (size_t)r * lda + ck + (t & 63) * 4);
            *(float4*)(Af + r * 258 + (t & 63) * 4) = v;
        }
        __syncthreads();
        const float* w0 = W + (size_t)oA * ldw + ck;
        const float* w1 = W + (size_t)oB * ldw + ck;
        const float* ar = Af + s * 258;
#pragma unroll 8
        for (int k4 = 0; k4 < 64; k4++) {
            f32x4 a4 = *(const f32x4*)(ar + k4 * 4);
            float4 v0 = *(const float4*)(w0 + k4 * 4);
            float4 v1 = *(const float4*)(w1 + k4 * 4);
            acc0 += a4[0] * v0.x + a4[1] * v0.y + a4[2] * v0.z + a4[3] * v0.w;
            acc1 += a4[0] * v1.x + a4[1] * v1.y + a4[2] * v1.z + a4[3] * v1.w;
        }
    }
    C[s * DIM_ + oA] = acc0 + (bias ? bias[oA] : 0.f);
    C[s * DIM_ + oB] = acc1 + (bias ? bias[oB] : 0.f);
}

// ==== pre-pass 1: {W2 panel (MFMA-fragment order) | M_lT | P_e} =============
__global__ __launch_bounds__(256) void k_pre1(
    const float* __restrict__ W2, const float* __restrict__ W_l,
    const float* __restrict__ W1, const float* __restrict__ P_f,
    const float* __restrict__ W_p,
    char* __restrict__ panel, ushort* __restrict__ MlT, float* __restrict__ P_e) {
    __shared__ float lbuf[64 * 258];       // 66048 B (union: w1r uses 16KB)
    int b = blockIdx.x, t = threadIdx.x;
    if (b < 128) {
        int c = b * 256 + t;                   // 32768 16B-chunks
        int o = c >> 6, rem = c & 63, kt = rem >> 2, kslot = rem & 3;
        const float* src = W2 + o * DIM_ + kt * BK + kslot * 8;
        float4 v0 = *(const float4*)src;
        float4 v1 = *(const float4*)(src + 4);
        union { ushort u[8]; short8 v; } pk;
        pk.u[0] = f2bf(v0.x); pk.u[1] = f2bf(v0.y); pk.u[2] = f2bf(v0.z); pk.u[3] = f2bf(v0.w);
        pk.u[4] = f2bf(v1.x); pk.u[5] = f2bf(v1.y); pk.u[6] = f2bf(v1.z); pk.u[7] = f2bf(v1.w);
        *(short8*)(panel + kt * 32768 + (o >> 4) * 1024 + kslot * 256 + (o & 15) * 16) = pk.v;
    } else if (b < 320) {
        float (*w1r)[DIM_] = (float (*)[DIM_])lbuf;
        int bx = b - 128;
        int o0 = (bx / 3) * 8;
        int ld = (bx % 3) * 256 + t;
        for (int i = t; i < 8 * DIM_; i += 256)
            w1r[i >> 9][i & 511] = W1[(o0 + (i >> 9)) * (2 * DIM_) + DIM_ + (i & 511)];
        __syncthreads();
        float acc[8] = {};
        for (int dim = 0; dim < DIM_; dim += 4) {   // b128 LDS reads
            float wl0 = W_l[(dim + 0) * LD_ + ld];
            float wl1 = W_l[(dim + 1) * LD_ + ld];
            float wl2 = W_l[(dim + 2) * LD_ + ld];
            float wl3 = W_l[(dim + 3) * LD_ + ld];
#pragma unroll
            for (int oi = 0; oi < 8; oi++) {
                f32x4 wv = *(const f32x4*)&w1r[oi][dim];
                acc[oi] += wv[0] * wl0 + wv[1] * wl1 + wv[2] * wl2 + wv[3] * wl3;
            }
        }
#pragma unroll
        for (int oi = 0; oi < 8; oi++) MlT[(o0 + oi) * LD_ + ld] = f2bf(acc[oi]);
    } else {
        proj8(lbuf, P_f, PD_, PD_, W_p, PD_, nullptr, P_e, (b - 320) * 8, t);
    }
}

// ==== pre-pass 2: {hpb = P_e @ W1p.T + b1 | hlB = bf16(emb[L]) @ MlT} =======
__global__ __launch_bounds__(256) void k_pre2(
    const float* __restrict__ P_e, const float* __restrict__ W1,
    const float* __restrict__ b1, const float* __restrict__ emb,
    const int* __restrict__ L, const ushort* __restrict__ MlT,
    float* __restrict__ hpb, ushort* __restrict__ hlB) {
    __shared__ float lbuf[64 * 258];
    int b = blockIdx.x, t = threadIdx.x;
    if (b < 64) {
        proj8(lbuf, P_e, DIM_, DIM_, W1, 2 * DIM_, b1, hpb, b * 8, t);
    } else {
        int hb = b - 64;                      // 0..313
        int rblk = hb % HL_RT, oh = hb / HL_RT;
        int r0 = rblk * 32;
        int w = t >> 6, l = t & 63, lg = l >> 4, ll = l & 15;
        const float* arow[2];
#pragma unroll
        for (int mt = 0; mt < 2; mt++) {
            int r = r0 + mt * 16 + ll;
            if (r >= NL_) r = NL_ - 1;
            arow[mt] = emb + (size_t)L[r] * LD_ + lg * 8;
        }
        f32x4 acc[2][4] = {};
        for (int k = 0; k < LD_; k += 32) {
            short8 a[2], bf[4];
#pragma unroll
            for (int mt = 0; mt < 2; mt++) {
                float4 v0 = *(const float4*)(arow[mt] + k);
                float4 v1 = *(const float4*)(arow[mt] + k + 4);
                union { ushort u[8]; short8 v; } pk;
                pk.u[0] = f2bf(v0.x); pk.u[1] = f2bf(v0.y);
                pk.u[2] = f2bf(v0.z); pk.u[3] = f2bf(v0.w);
                pk.u[4] = f2bf(v1.x); pk.u[5] = f2bf(v1.y);
                pk.u[6] = f2bf(v1.z); pk.u[7] = f2bf(v1.w);
                a[mt] = pk.v;
            }
#pragma unroll
            for (int ot = 0; ot < 4; ot++) {
                int o = oh * 256 + w * 64 + ot * 16 + ll;
                bf[ot] = *(const short8*)(MlT + o * LD_ + k + lg * 8);
            }
#pragma unroll
            for (int mt = 0; mt < 2; mt++)
#pragma unroll
                for (int ot = 0; ot < 4; ot++)
                    acc[mt][ot] = __builtin_amdgcn_mfma_f32_16x16x32_bf16(a[mt], bf[ot], acc[mt][ot], 0, 0, 0);
        }
#pragma unroll
        for (int mt = 0; mt < 2; mt++)
#pragma unroll
            for (int ot = 0; ot < 4; ot++)
#pragma unroll
                for (int reg = 0; reg < 4; reg++) {
                    int r = r0 + mt * 16 + lg * 4 + reg;
                    if (r < NL_)
                        hlB[(size_t)r * DIM_ + oh * 256 + w * 64 + ot * 16 + ll] = f2bf(acc[mt][ot][reg]);
                }
    }
}

// ==== main: BM=256 (4s x 64n) x BN=256 — halves unique B traffic ============
// 8 waves (4M x 2N), wave tile 64x128, acc[4][8] (128 AGPR).
// B: unique bytes/k-step 16KB (was 32) -> L1-resident, 4 waves share each
// wc slice. A: K-window 128 double-buffer (2 x 64KB LDS, r15 schedule);
// thread packs 2 rows/sub-tile sharing the same n (one hl load, two hp).
// Slot A light (hv only; hp loaded at pack), slot B full -> r15 reg budget.
__global__ __launch_bounds__(512, 2) void k_main2(
    const ushort* __restrict__ hlB, const float* __restrict__ hpb,
    const char* __restrict__ panel, const float* __restrict__ b2,
    const float* __restrict__ W3, float* __restrict__ part) {
    __shared__ f32x4 ldsv[8192];            // 131072 B: A dbuf 2 x 64KB
    char* lds = (char*)ldsv;
    const int t = threadIdx.x;
    const int n0 = blockIdx.x * 64, s0 = blockIdx.y * 4, oh = blockIdx.z;
    const int w = t >> 6, lane = t & 63, lg = lane >> 4, ll = lane & 15;
    const int wr = w >> 1, wc = w & 1;      // 4M x 2N wave grid

    // A-staging: thread t owns chunks (row=t>>2, ks=t&3) and (+128 rows)
    const int arow = t >> 2, akslot = t & 3;
    int an = n0 + (arow & 63); if (an >= NL_) an = NL_ - 1;
    const ushort* hlsrc = hlB + (size_t)an * DIM_ + akslot * 8;       // shared by both rows
    const float*  hpA = hpb + (s0 + (t >> 8)) * DIM_ + akslot * 8;    // row a: s0+0/1
    const float*  hpB = hpA + 2 * DIM_;                               // row b: +2
    const int awz = swz(arow, akslot);                                // row b: +8192

    const int abase = swz(wr * 64 + ll, lg);                 // + mt*1024
    const char* bbase = panel + (oh * 16 + wc * 8) * 1024 + lane * 16;

    f32x4 acc[4][8] = {};

    auto packCore = [&](int buf, int sub, short8 hv,
                        f32x4 a0, f32x4 a1, f32x4 b0, f32x4 b1) {
        union { __hip_bfloat162 h2[4]; short8 v; } pk;
        float x[8];
#pragma unroll
        for (int e = 0; e < 4; e++) {
            float u0 = bf2f((ushort)hv[e]) + a0[e];
            float u1 = bf2f((ushort)hv[4 + e]) + a1[e];
            x[e] = u0 > 0.f ? u0 : 0.f;
            x[4 + e] = u1 > 0.f ? u1 : 0.f;
        }
#pragma unroll
        for (int e = 0; e < 4; e++)
            pk.h2[e] = __float22bfloat162_rn(make_float2(x[2 * e], x[2 * e + 1]));
        *(short8*)(lds + buf * 65536 + sub * 16384 + awz) = pk.v;
#pragma unroll
        for (int e = 0; e < 4; e++) {
            float u0 = bf2f((ushort)hv[e]) + b0[e];
            float u1 = bf2f((ushort)hv[4 + e]) + b1[e];
            x[e] = u0 > 0.f ? u0 : 0.f;
            x[4 + e] = u1 > 0.f ? u1 : 0.f;
        }
#pragma unroll
        for (int e = 0; e < 4; e++)
            pk.h2[e] = __float22bfloat162_rn(make_float2(x[2 * e], x[2 * e + 1]));
        *(short8*)(lds + buf * 65536 + sub * 16384 + 8192 + awz) = pk.v;
    };
    auto packLazy = [&](int buf, int sub, short8 hv, int ks) {  // hp at pack
        f32x4 a0 = *(const f32x4*)(hpA + ks * BK);
        f32x4 a1 = *(const f32x4*)(hpA + ks * BK + 4);
        f32x4 b0 = *(const f32x4*)(hpB + ks * BK);
        f32x4 b1 = *(const f32x4*)(hpB + ks * BK + 4);
        packCore(buf, sub, hv, a0, a1, b0, b1);
    };

    // ---- prologue: pack window 0 (4 subs, 2 groups); one barrier ----
#pragma unroll
    for (int g = 0; g < 2; g++) {
#pragma unroll
        for (int i = 0; i < 2; i++) {
            int ks = g * 2 + i;
            short8 hv = *(const short8*)(hlsrc + ks * BK);
            packLazy(0, ks, hv, ks);
        }
        __builtin_amdgcn_sched_barrier(0);
    }
    asm volatile("s_waitcnt lgkmcnt(0)" ::: "memory");
    __builtin_amdgcn_s_barrier();

    short8 bq0[4], bq1[4];
#pragma unroll
    for (int j = 0; j < 4; j++) bq0[j] = *(const short8*)(bbase + j * 1024);

    // stagger slots: A light (hv only), B full (hv + 4 hp vecs)
    short8 hvA, hvB; f32x4 pB0a, pB1a, pB0b, pB1b;

    for (int win = 0; win < NWIN4; win++) {
        const char* A = lds + (win & 1) * 65536;
        const int nxt = (win & 1) ^ 1;
        const bool more = (win + 1 < NWIN4);
#pragma unroll
        for (int i = 0; i < 4; i++) {
            const int ks = 4 * win + i;
            const char* bks = bbase + ks * 32768;
            short8 a[4];
#pragma unroll
            for (int mt = 0; mt < 4; mt++)
                a[mt] = *(const short8*)(A + i * 16384 + abase + mt * 1024);
#pragma unroll
            for (int j = 0; j < 4; j++) bq1[j] = *(const short8*)(bks + 4096 + j * 1024);
            // staggered next-window A: load sub i', pack sub (i-1)'
            if (more) {
                if (i == 0) {
                    hvA = *(const short8*)(hlsrc + (ks + 4) * BK);
                } else if (i == 1) {
                    packLazy(nxt, 0, hvA, ks + 3);
                    hvB = *(const short8*)(hlsrc + (ks + 4) * BK);
                    pB0a = *(const f32x4*)(hpA + (ks + 4) * BK);
                    pB1a = *(const f32x4*)(hpA + (ks + 4) * BK + 4);
                    pB0b = *(const f32x4*)(hpB + (ks + 4) * BK);
                    pB1b = *(const f32x4*)(hpB + (ks + 4) * BK + 4);
                } else if (i == 2) {
                    packCore(nxt, 1, hvB, pB0a, pB1a, pB0b, pB1b);
                    hvA = *(const short8*)(hlsrc + (ks + 4) * BK);
                } else {
                    packLazy(nxt, 2, hvA, ks + 3);
                    hvB = *(const short8*)(hlsrc + (ks + 4) * BK);
                    pB0a = *(const f32x4*)(hpA + (ks + 4) * BK);
                    pB1a = *(const f32x4*)(hpA + (ks + 4) * BK + 4);
                    pB0b = *(const f32x4*)(hpB + (ks + 4) * BK);
                    pB1b = *(const f32x4*)(hpB + (ks + 4) * BK + 4);
                }
            }
            __builtin_amdgcn_s_setprio(1);
#pragma unroll
            for (int mt = 0; mt < 4; mt++)
#pragma unroll
                for (int j = 0; j < 4; j++)
                    acc[mt][j] = __builtin_amdgcn_mfma_f32_16x16x32_bf16(a[mt], bq0[j], acc[mt][j], 0, 0, 0);
            __builtin_amdgcn_s_setprio(0);
            if (!(win == NWIN4 - 1 && i == 3))
#pragma unroll
                for (int j = 0; j < 4; j++)
                    bq0[j] = *(const short8*)(bbase + (ks + 1) * 32768 + j * 1024);
            __builtin_amdgcn_s_setprio(1);
#pragma unroll
            for (int mt = 0; mt < 4; mt++)
#pragma unroll
                for (int j = 0; j < 4; j++)
                    acc[mt][4 + j] = __builtin_amdgcn_mfma_f32_16x16x32_bf16(a[mt], bq1[j], acc[mt][4 + j], 0, 0, 0);
            __builtin_amdgcn_s_setprio(0);
        }
        if (more) packCore(nxt, 3, hvB, pB0a, pB1a, pB0b, pB1b);
        asm volatile("s_waitcnt lgkmcnt(0)" ::: "memory");
        __builtin_amdgcn_s_barrier();
    }

    // ---- epilogue: relu(acc+b2)*W3, reduce over this 256-o half ----
    float* logit = (float*)lds;
    if (t < 256) logit[t] = 0.f;
    __syncthreads();
#pragma unroll
    for (int mt = 0; mt < 4; mt++) {
        float p4[4] = { 0.f, 0.f, 0.f, 0.f };
#pragma unroll
        for (int ot = 0; ot < 8; ot++) {
            int o = oh * 256 + wc * 128 + ot * 16 + ll;
            float bb = b2[o], w3 = W3[o];
#pragma unroll
            for (int reg = 0; reg < 4; reg++) {
                float v = acc[mt][ot][reg] + bb;
                v = v > 0.f ? v : 0.f;
                p4[reg] += v * w3;
            }
        }
#pragma unroll
        for (int m = 1; m < 16; m <<= 1)
#pragma unroll
            for (int reg = 0; reg < 4; reg++) p4[reg] += __shfl_xor(p4[reg], m, 64);
        if (ll == 0)
#pragma unroll
            for (int reg = 0; reg < 4; reg++)
                atomicAdd(&logit[wr * 64 + mt * 16 + lg * 4 + reg], p4[reg]);
    }
    __syncthreads();
    if (t < 256) {
        int n = n0 + (t & 63);
        int s = s0 + (t >> 6);
        if (n < NL_)
            part[(size_t)oh * (S_ * NL_) + (size_t)s * NL_ + n] = logit[t];
    }
}

// ---- combine the two o-half partials ---------------------------------------
__global__ void k_comb(const float* __restrict__ part, const float* __restrict__ b3,
                       float* __restrict__ out) {
    int i = blockIdx.x * 256 + threadIdx.x;
    if (i < S_ * NL_) out[i] = part[i] + part[S_ * NL_ + i] + b3[0];
}

extern "C" void kernel_launch(void* const* d_in, const int* in_sizes, int n_in,
                              void* d_out, int out_size, void* d_ws, size_t ws_size,
                              hipStream_t stream) {
    const float* P_f = (const float*)d_in[0];
    const float* emb = (const float*)d_in[1];
    const float* W_p = (const float*)d_in[2];
    const float* W_l = (const float*)d_in[3];
    const float* W1  = (const float*)d_in[4];
    const float* b1  = (const float*)d_in[5];
    const float* W2  = (const float*)d_in[6];
    const float* b2  = (const float*)d_in[7];
    const float* W3  = (const float*)d_in[8];
    const float* b3  = (const float*)d_in[9];
    const int*   L   = (const int*)d_in[10];
    float* out = (float*)d_out;

    char* ws = (char*)d_ws;
    size_t off = 0;
    auto alloc = [&](size_t bytes) {
        void* p = ws + off;
        off = (off + bytes + 255) & ~(size_t)255;
        return p;
    };
    char*   panel = (char*)alloc((size_t)KSTEPS * 32768);            // 512 KB
    ushort* MlT   = (ushort*)alloc((size_t)OD_ * LD_ * 2);           // 768 KB
    float*  P_e   = (float*)alloc((size_t)S_ * DIM_ * 4);
    float*  hpb   = (float*)alloc((size_t)S_ * DIM_ * 4);
    ushort* hlB   = (ushort*)alloc((size_t)NL_ * DIM_ * 2);          // 5.12 MB
    float*  part  = (float*)alloc((size_t)2 * S_ * NL_ * 4);         // 2.56 MB

    k_pre1<<<384, 256, 0, stream>>>(W2, W_l, W1, P_f, W_p, panel, MlT, P_e);
    k_pre2<<<378, 256, 0, stream>>>(P_e, W1, b1, emb, L, MlT, hpb, hlB);
    k_main2<<<dim3(NT_M, 16, 2), 512, 0, stream>>>(hlB, hpb, panel, b2, W3, part);
    k_comb<<<(S_ * NL_ + 255) / 256, 256, 0, stream>>>(part, b3, out);
}

// Round 18
// 238.564 us; speedup vs baseline: 1.1238x; 1.1238x over previous
//
#include <hip/hip_runtime.h>
#include <hip/hip_bf16.h>

typedef short short8 __attribute__((ext_vector_type(8)));
typedef float f32x4 __attribute__((ext_vector_type(4)));

#define S_   64
#define NL_  5000
#define PD_  1024
#define LD_  768
#define DIM_ 512
#define OD_  512

#define BK     32          // panel/pack granularity (unchanged layouts)
#define KSTEPS 16          // DIM_/BK
#define NT_M   79          // ceil(5000/64) n-tiles for main
#define HL_RT  157         // ceil(5000/32) row-tiles for hl

__device__ __forceinline__ ushort f2bf(float f) {
    union { float f; unsigned u; } v; v.f = f;
    unsigned r = v.u + 0x7fffu + ((v.u >> 16) & 1u);   // RNE
    return (ushort)(r >> 16);
}
__device__ __forceinline__ float bf2f(ushort h) {
    union { unsigned u; float f; } v; v.u = ((unsigned)h) << 16;
    return v.f;
}
// XOR swizzle for 64B-stride row tiles: conflict-free for packA write
// (4 lanes/row x 4 kslots) and the 16-row x 4-kslot fragment read (measured
// 0 conflicts r6/r9/r10/r13/r15/r16). swz(row+16,k) == swz(row,k)+1024.
__device__ __forceinline__ int swz(int row, int kslot) {
    return (row * 64 + kslot * 16) ^ (((row >> 1) & 7) << 4);
}

// ---- coalesced small GEMM: C[s][o0..o0+7] = A[64][K] @ W[.][K]^T (+bias) ---
__device__ __forceinline__ void proj8(
    float* Af /* [64][258] */, const float* __restrict__ A, int lda, int K,
    const float* __restrict__ W, int ldw, const float* __restrict__ bias,
    float* __restrict__ C, int o0, int t) {
    const int s = t & 63, og = t >> 6;
    const int oA = o0 + og * 2, oB = oA + 1;
    float acc0 = 0.f, acc1 = 0.f;
    for (int ck = 0; ck < K; ck += 256) {
        __syncthreads();
#pragma unroll
        for (int it = 0; it < 16; it++) {
            int r = it * 4 + (t >> 6);
            float4 v = *(const float4*)(A + (size_t)r * lda + ck + (t & 63) * 4);
            *(float4*)(Af + r * 258 + (t & 63) * 4) = v;
        }
        __syncthreads();
        const float* w0 = W + (size_t)oA * ldw + ck;
        const float* w1 = W + (size_t)oB * ldw + ck;
        const float* ar = Af + s * 258;
#pragma unroll 8
        for (int k4 = 0; k4 < 64; k4++) {
            f32x4 a4 = *(const f32x4*)(ar + k4 * 4);
            float4 v0 = *(const float4*)(w0 + k4 * 4);
            float4 v1 = *(const float4*)(w1 + k4 * 4);
            acc0 += a4[0] * v0.x + a4[1] * v0.y + a4[2] * v0.z + a4[3] * v0.w;
            acc1 += a4[0] * v1.x + a4[1] * v1.y + a4[2] * v1.z + a4[3] * v1.w;
        }
    }
    C[s * DIM_ + oA] = acc0 + (bias ? bias[oA] : 0.f);
    C[s * DIM_ + oB] = acc1 + (bias ? bias[oB] : 0.f);
}

// ==== pre-pass 1: {W2 panel (MFMA-fragment order) | M_lT | P_e} =============
__global__ __launch_bounds__(256) void k_pre1(
    const float* __restrict__ W2, const float* __restrict__ W_l,
    const float* __restrict__ W1, const float* __restrict__ P_f,
    const float* __restrict__ W_p,
    char* __restrict__ panel, ushort* __restrict__ MlT, float* __restrict__ P_e) {
    __shared__ float lbuf[64 * 258];       // 66048 B (union: w1r uses 16KB)
    int b = blockIdx.x, t = threadIdx.x;
    if (b < 128) {
        int c = b * 256 + t;                   // 32768 16B-chunks
        int o = c >> 6, rem = c & 63, kt = rem >> 2, kslot = rem & 3;
        const float* src = W2 + o * DIM_ + kt * BK + kslot * 8;
        float4 v0 = *(const float4*)src;
        float4 v1 = *(const float4*)(src + 4);
        union { ushort u[8]; short8 v; } pk;
        pk.u[0] = f2bf(v0.x); pk.u[1] = f2bf(v0.y); pk.u[2] = f2bf(v0.z); pk.u[3] = f2bf(v0.w);
        pk.u[4] = f2bf(v1.x); pk.u[5] = f2bf(v1.y); pk.u[6] = f2bf(v1.z); pk.u[7] = f2bf(v1.w);
        *(short8*)(panel + kt * 32768 + (o >> 4) * 1024 + kslot * 256 + (o & 15) * 16) = pk.v;
    } else if (b < 320) {
        float (*w1r)[DIM_] = (float (*)[DIM_])lbuf;
        int bx = b - 128;
        int o0 = (bx / 3) * 8;
        int ld = (bx % 3) * 256 + t;
        for (int i = t; i < 8 * DIM_; i += 256)
            w1r[i >> 9][i & 511] = W1[(o0 + (i >> 9)) * (2 * DIM_) + DIM_ + (i & 511)];
        __syncthreads();
        float acc[8] = {};
        for (int dim = 0; dim < DIM_; dim += 4) {   // b128 LDS reads (4x fewer)
            float wl0 = W_l[(dim + 0) * LD_ + ld];
            float wl1 = W_l[(dim + 1) * LD_ + ld];
            float wl2 = W_l[(dim + 2) * LD_ + ld];
            float wl3 = W_l[(dim + 3) * LD_ + ld];
#pragma unroll
            for (int oi = 0; oi < 8; oi++) {
                f32x4 wv = *(const f32x4*)&w1r[oi][dim];
                acc[oi] += wv[0] * wl0 + wv[1] * wl1 + wv[2] * wl2 + wv[3] * wl3;
            }
        }
#pragma unroll
        for (int oi = 0; oi < 8; oi++) MlT[(o0 + oi) * LD_ + ld] = f2bf(acc[oi]);
    } else {
        proj8(lbuf, P_f, PD_, PD_, W_p, PD_, nullptr, P_e, (b - 320) * 8, t);
    }
}

// ==== pre-pass 2: {hpb = P_e @ W1p.T + b1 | hlB = bf16(emb[L]) @ MlT} =======
__global__ __launch_bounds__(256) void k_pre2(
    const float* __restrict__ P_e, const float* __restrict__ W1,
    const float* __restrict__ b1, const float* __restrict__ emb,
    const int* __restrict__ L, const ushort* __restrict__ MlT,
    float* __restrict__ hpb, ushort* __restrict__ hlB) {
    __shared__ float lbuf[64 * 258];
    int b = blockIdx.x, t = threadIdx.x;
    if (b < 64) {
        proj8(lbuf, P_e, DIM_, DIM_, W1, 2 * DIM_, b1, hpb, b * 8, t);
    } else {
        int hb = b - 64;                      // 0..313
        int rblk = hb % HL_RT, oh = hb / HL_RT;
        int r0 = rblk * 32;
        int w = t >> 6, l = t & 63, lg = l >> 4, ll = l & 15;
        const float* arow[2];
#pragma unroll
        for (int mt = 0; mt < 2; mt++) {
            int r = r0 + mt * 16 + ll;
            if (r >= NL_) r = NL_ - 1;
            arow[mt] = emb + (size_t)L[r] * LD_ + lg * 8;
        }
        f32x4 acc[2][4] = {};
        for (int k = 0; k < LD_; k += 32) {
            short8 a[2], bf[4];
#pragma unroll
            for (int mt = 0; mt < 2; mt++) {
                float4 v0 = *(const float4*)(arow[mt] + k);
                float4 v1 = *(const float4*)(arow[mt] + k + 4);
                union { ushort u[8]; short8 v; } pk;
                pk.u[0] = f2bf(v0.x); pk.u[1] = f2bf(v0.y);
                pk.u[2] = f2bf(v0.z); pk.u[3] = f2bf(v0.w);
                pk.u[4] = f2bf(v1.x); pk.u[5] = f2bf(v1.y);
                pk.u[6] = f2bf(v1.z); pk.u[7] = f2bf(v1.w);
                a[mt] = pk.v;
            }
#pragma unroll
            for (int ot = 0; ot < 4; ot++) {
                int o = oh * 256 + w * 64 + ot * 16 + ll;
                bf[ot] = *(const short8*)(MlT + o * LD_ + k + lg * 8);
            }
#pragma unroll
            for (int mt = 0; mt < 2; mt++)
#pragma unroll
                for (int ot = 0; ot < 4; ot++)
                    acc[mt][ot] = __builtin_amdgcn_mfma_f32_16x16x32_bf16(a[mt], bf[ot], acc[mt][ot], 0, 0, 0);
        }
#pragma unroll
        for (int mt = 0; mt < 2; mt++)
#pragma unroll
            for (int ot = 0; ot < 4; ot++)
#pragma unroll
                for (int reg = 0; reg < 4; reg++) {
                    int r = r0 + mt * 16 + lg * 4 + reg;
                    if (r < NL_)
                        hlB[(size_t)r * DIM_ + oh * 256 + w * 64 + ot * 16 + ll] = f2bf(acc[mt][ot][reg]);
                }
    }
}

// ==== main: BM=128 x BN=512 — SINGLE A BUFFER, ZERO IN-LOOP BARRIERS ========
// 8 waves (2M x 4N), wave tile 64x128, acc[4][8] (128 AGPR).
// A: whole 128x512 bf16 tile (128KB LDS) packed ONCE in the prologue
// (16 sub-tiles in r13/r15's exact swizzled layout, grouped 4-at-a-time to
// cap register pressure), one lgkm+barrier. K-loop is then READ-ONLY on LDS:
// no WAR hazards, no packA, no barriers, no waitcnt — compiler pipelines
// freely across k-steps; 2 waves/SIMD co-schedule covers B L2 latency.
// B: fragment-ordered panel register quads (r10 path, unchanged).
__global__ __launch_bounds__(512, 2) void k_main2(
    const ushort* __restrict__ hlB, const float* __restrict__ hpb,
    const char* __restrict__ panel, const float* __restrict__ b2,
    const float* __restrict__ W3, const float* __restrict__ b3,
    float* __restrict__ out) {
    __shared__ f32x4 ldsv[8192];            // 131072 B: A single buffer
    char* lds = (char*)ldsv;
    const int t = threadIdx.x;
    const int n0 = blockIdx.x * 64, s0 = blockIdx.y * 2;
    const int w = t >> 6, lane = t & 63, lg = lane >> 4, ll = lane & 15;
    const int wr = w >> 2, wc = w & 3;      // 2M x 4N wave grid

    // A-staging: thread t owns one 16B chunk per sub-tile (row=t>>2, ks=t&3)
    const int arow = t >> 2, akslot = t & 3;
    int an = n0 + (arow & 63); if (an >= NL_) an = NL_ - 1;
    const ushort* hlsrc = hlB + (size_t)an * DIM_ + akslot * 8;
    const float*  hpsrc = hpb + (s0 + (arow >> 6)) * DIM_ + akslot * 8;
    const int awz = swz(arow, akslot);

    const int abase = swz(wr * 64 + ll, lg);                 // + mt*1024
    const char* bbase = panel + (wc * 8) * 1024 + lane * 16;

    f32x4 acc[4][8] = {};

    auto packSub = [&](int sub, short8 hv, f32x4 p0, f32x4 p1) {
        float x[8];
#pragma unroll
        for (int e = 0; e < 4; e++) {
            float a0 = bf2f((ushort)hv[e]) + p0[e];
            float a1 = bf2f((ushort)hv[4 + e]) + p1[e];
            x[e]     = a0 > 0.f ? a0 : 0.f;
            x[4 + e] = a1 > 0.f ? a1 : 0.f;
        }
        union { __hip_bfloat162 h2[4]; short8 v; } pk;
#pragma unroll
        for (int e = 0; e < 4; e++)
            pk.h2[e] = __float22bfloat162_rn(make_float2(x[2 * e], x[2 * e + 1]));
        *(short8*)(lds + sub * 8192 + awz) = pk.v;
    };

    // ---- prologue: pack ALL 16 A sub-tiles (4 groups of 4); one barrier ----
#pragma unroll
    for (int g = 0; g < 4; g++) {
        short8 hv[4]; f32x4 p0[4], p1[4];
#pragma unroll
        for (int i = 0; i < 4; i++) {
            int ks = g * 4 + i;
            hv[i] = *(const short8*)(hlsrc + ks * BK);
            p0[i] = *(const f32x4*)(hpsrc + ks * BK);
            p1[i] = *(const f32x4*)(hpsrc + ks * BK + 4);
        }
#pragma unroll
        for (int i = 0; i < 4; i++) packSub(g * 4 + i, hv[i], p0[i], p1[i]);
        __builtin_amdgcn_sched_barrier(0);   // cap in-flight registers
    }
    asm volatile("s_waitcnt lgkmcnt(0)" ::: "memory");
    __builtin_amdgcn_s_barrier();

    short8 bq0[4], bq1[4];
#pragma unroll
    for (int j = 0; j < 4; j++) bq0[j] = *(const short8*)(bbase + j * 1024);

    // ---- barrier-free K-loop ----
    for (int ks = 0; ks < KSTEPS; ks++) {
        const char* A = lds + ks * 8192;
        const char* bks = bbase + ks * 32768;
        short8 a[4];
#pragma unroll
        for (int mt = 0; mt < 4; mt++)
            a[mt] = *(const short8*)(A + abase + mt * 1024);
#pragma unroll
        for (int j = 0; j < 4; j++) bq1[j] = *(const short8*)(bks + 4096 + j * 1024);
        __builtin_amdgcn_s_setprio(1);
#pragma unroll
        for (int mt = 0; mt < 4; mt++)
#pragma unroll
            for (int j = 0; j < 4; j++)
                acc[mt][j] = __builtin_amdgcn_mfma_f32_16x16x32_bf16(a[mt], bq0[j], acc[mt][j], 0, 0, 0);
        __builtin_amdgcn_s_setprio(0);
        if (ks + 1 < KSTEPS)
#pragma unroll
            for (int j = 0; j < 4; j++)
                bq0[j] = *(const short8*)(bks + 32768 + j * 1024);
        __builtin_amdgcn_s_setprio(1);
#pragma unroll
        for (int mt = 0; mt < 4; mt++)
#pragma unroll
            for (int j = 0; j < 4; j++)
                acc[mt][4 + j] = __builtin_amdgcn_mfma_f32_16x16x32_bf16(a[mt], bq1[j], acc[mt][4 + j], 0, 0, 0);
        __builtin_amdgcn_s_setprio(0);
    }

    // ---- epilogue: relu(acc+b2)*W3, reduce over o; direct out write ----
    __syncthreads();                        // A reads done; reuse LDS front
    float* logit = (float*)lds;
    if (t < 128) logit[t] = 0.f;
    __syncthreads();
#pragma unroll
    for (int mt = 0; mt < 4; mt++) {
        float p4[4] = { 0.f, 0.f, 0.f, 0.f };
#pragma unroll
        for (int ot = 0; ot < 8; ot++) {
            int o = wc * 128 + ot * 16 + ll;
            float bb = b2[o], w3 = W3[o];
#pragma unroll
            for (int reg = 0; reg < 4; reg++) {
                float v = acc[mt][ot][reg] + bb;
                v = v > 0.f ? v : 0.f;
                p4[reg] += v * w3;
            }
        }
#pragma unroll
        for (int m = 1; m < 16; m <<= 1)
#pragma unroll
            for (int reg = 0; reg < 4; reg++) p4[reg] += __shfl_xor(p4[reg], m, 64);
        if (ll == 0)
#pragma unroll
            for (int reg = 0; reg < 4; reg++)
                atomicAdd(&logit[wr * 64 + mt * 16 + lg * 4 + reg], p4[reg]);
    }
    __syncthreads();
    if (t < 128) {
        int n = n0 + (t & 63);
        int s = s0 + (t >> 6);
        if (n < NL_) out[(size_t)s * NL_ + n] = logit[t] + b3[0];
    }
}

extern "C" void kernel_launch(void* const* d_in, const int* in_sizes, int n_in,
                              void* d_out, int out_size, void* d_ws, size_t ws_size,
                              hipStream_t stream) {
    const float* P_f = (const float*)d_in[0];
    const float* emb = (const float*)d_in[1];
    const float* W_p = (const float*)d_in[2];
    const float* W_l = (const float*)d_in[3];
    const float* W1  = (const float*)d_in[4];
    const float* b1  = (const float*)d_in[5];
    const float* W2  = (const float*)d_in[6];
    const float* b2  = (const float*)d_in[7];
    const float* W3  = (const float*)d_in[8];
    const float* b3  = (const float*)d_in[9];
    const int*   L   = (const int*)d_in[10];
    float* out = (float*)d_out;

    char* ws = (char*)d_ws;
    size_t off = 0;
    auto alloc = [&](size_t bytes) {
        void* p = ws + off;
        off = (off + bytes + 255) & ~(size_t)255;
        return p;
    };
    char*   panel = (char*)alloc((size_t)KSTEPS * 32768);            // 512 KB
    ushort* MlT   = (ushort*)alloc((size_t)OD_ * LD_ * 2);           // 768 KB
    float*  P_e   = (float*)alloc((size_t)S_ * DIM_ * 4);
    float*  hpb   = (float*)alloc((size_t)S_ * DIM_ * 4);
    ushort* hlB   = (ushort*)alloc((size_t)NL_ * DIM_ * 2);          // 5.12 MB

    k_pre1<<<384, 256, 0, stream>>>(W2, W_l, W1, P_f, W_p, panel, MlT, P_e);
    k_pre2<<<378, 256, 0, stream>>>(P_e, W1, b1, emb, L, MlT, hpb, hlB);
    k_main2<<<dim3(NT_M, 32), 512, 0, stream>>>(hlB, hpb, panel, b2, W3, b3, out);
}